// Round 15
// baseline (337.014 us; speedup 1.0000x reference)
//
#include <hip/hip_runtime.h>
#include <hip/hip_bf16.h>

// Flash attention fwd, masked, fp32 I/O, bf16 MFMA compute.
// n=8 heads, q=s=4096, d=v=64.
// Round 15: TLP with staging held constant. 1024-thread blocks (16 waves =
// 4 q-tiles x 4 s-quarters), grid 256 = 1 block/CU -> 4 waves/SIMD (was 2),
// K/V staged once per block per 128-s phase (same per-CU staging as r14).
// Per wave per phase: one 32x32 tile (4 QK^T + 4 PV MFMAs), in-register P
// exchange (shfl_xor 32), defer-max, LDS-only barrier. 4-way s-merge via a
// 2-round LDS tree aliased onto the dead K/V buffers.

#define NHEADS 8
#define QLEN   4096
#define SLEN   4096
#define DDIM   64
#define VDIM   64
#define PBLK   128                 // s per phase
#define QBLK   128
#define NPHASE (SLEN / PBLK)

typedef __bf16          bf16x8 __attribute__((ext_vector_type(8)));
typedef float           f32x4  __attribute__((ext_vector_type(4)));
typedef float           f32x16 __attribute__((ext_vector_type(16)));
typedef unsigned int    u32x4  __attribute__((ext_vector_type(4)));

#define KSWZ(s) (((s) & 7) << 4)
#define VSWZ(v) ((((v) >> 2) & 7) << 4)
#define CLAMPP(p) ((p) < NPHASE ? (p) : NPHASE - 1)

// LDS-only barrier: drain LDS ops, barrier, fence scheduler (rule #18).
#define LDS_BARRIER() do {                                          \
  asm volatile("s_waitcnt lgkmcnt(0)" ::: "memory");                \
  __builtin_amdgcn_s_barrier();                                     \
  __builtin_amdgcn_sched_barrier(0);                                \
} while (0)

__device__ __forceinline__ f32x16 zero16() {
  f32x16 z;
#pragma unroll
  for (int i = 0; i < 16; ++i) z[i] = 0.f;
  return z;
}
__device__ __forceinline__ unsigned short bfb(float x) {
  return __builtin_bit_cast(unsigned short, (__bf16)x);
}
__device__ __forceinline__ unsigned pk2(float a, float b) {
  return (unsigned)bfb(a) | ((unsigned)bfb(b) << 16);
}

// ---------------- in-kernel mask dtype detection ----------------
// i32 {0,1}: bytes 1,2 of every word zero -> 1.
// f32 {0,1.0f}: byte 0 of every word zero (0x3F800000 LE) -> 2.
// u8 bool: neither -> 0. Uniform across lanes/waves/blocks.
__device__ __forceinline__ int detect_mfmt(const unsigned char* __restrict__ M) {
  const int lane = threadIdx.x & 63;
  u32x4 w = *((const u32x4*)M + lane);
  unsigned o = w[0] | w[1] | w[2] | w[3];
  unsigned comb = ((o & 0x00FFFF00u) ? 1u : 0u) | ((o & 0x000000FFu) ? 2u : 0u);
  comb |= __shfl_xor((int)comb, 1);  comb |= __shfl_xor((int)comb, 2);
  comb |= __shfl_xor((int)comb, 4);  comb |= __shfl_xor((int)comb, 8);
  comb |= __shfl_xor((int)comb, 16); comb |= __shfl_xor((int)comb, 32);
  return ((comb & 1u) == 0u) ? 1 : (((comb & 2u) == 0u) ? 2 : 0);
}

template<bool U8>
__global__ __launch_bounds__(1024, 4)
void attn_fwd(const float* __restrict__ Qg, const float* __restrict__ Kg,
              const float* __restrict__ Vg, const unsigned char* __restrict__ Mg,
              float* __restrict__ Og)
{
  // One 64KB arena: K bufs at +0/+16K, V bufs at +32K/+48K; merge tree
  // aliases the whole arena after the main loop (2 slots x 32KB).
  __shared__ __align__(16) unsigned char LB[65536];
  __shared__ float mM[2][4][2][32];   // [slot][qtile][m,l][lq]

  {
    const int mfmt = detect_mfmt(Mg);
    if (U8 ? (mfmt != 0) : (mfmt == 0)) return;   // other instantiation handles it
  }

  const int tid   = threadIdx.x;
  const int wave  = tid >> 6;     // 0..15
  const int lane  = tid & 63;
  const int qtile = wave & 3;     // q sub-tile (32 q)
  const int sq    = wave >> 2;    // s-quarter (32 s of each 128-s phase)
  const int lq    = lane & 31;
  const int h     = lane >> 5;

  const int head = blockIdx.x;    // grid (8, 32): linear id % 8 == head -> one XCD per head
  const int qblk = blockIdx.y;

  const float* Qp = Qg + ((size_t)head * QLEN + (size_t)qblk * QBLK) * DDIM;
  const float* Kp = Kg + (size_t)head * SLEN * DDIM;
  const float* Vp = Vg + (size_t)head * SLEN * VDIM;
  float* Op = Og + ((size_t)head * QLEN + (size_t)qblk * QBLK) * DDIM;

  char* const Kb0 = (char*)LB;
  char* const Kb1 = (char*)LB + 16384;
  char* const Vb0 = (char*)LB + 32768;
  char* const Vb1 = (char*)LB + 49152;

  // ---- Q fragments (B-operand: col q = lq, k = 8h + i + 16kd), pre-scaled ----
  const float QSCALE = 0.125f * 1.44269504f;
  const int qrow = qtile * 32 + lq;
  bf16x8 qf[4];
#pragma unroll
  for (int kd = 0; kd < 4; ++kd) {
    const float* qp = Qp + (size_t)qrow * DDIM + 16 * kd + 8 * h;
    f32x4 a = *(const f32x4*)qp;
    f32x4 b = *(const f32x4*)(qp + 4);
    bf16x8 t;
#pragma unroll
    for (int j = 0; j < 4; ++j) { t[j] = (__bf16)(a[j] * QSCALE); t[4 + j] = (__bf16)(b[j] * QSCALE); }
    qf[kd] = t;
  }

  // this wave's mask row base: row qrow, s-offset sq*32
  const size_t mbase = ((size_t)head * QLEN + (size_t)qblk * QBLK + qrow) * SLEN
                     + (size_t)sq * 32;
  const unsigned char* mrow8  = Mg + mbase;
  const unsigned*      mrow32 = (const unsigned*)Mg + mbase;

  f32x16 oacc[2];
  oacc[0] = zero16(); oacc[1] = zero16();
  float m_run = -INFINITY;
  float l_run = 0.f;

  // staging regs: 1024 threads cover 128 rows x 8 floats (2 f32x4 each)
  f32x4 kpr0, kpr1, vpr0, vpr1;
  unsigned m8A[4],  m8B[4];      // U8 mask sets (template DCE)
  u32x4    m32A[4], m32B[4];

#define PREFETCH_KV(P)                                                         \
  {                                                                            \
    size_t b_ = (size_t)CLAMPP(P) * PBLK;                                      \
    int sr_ = tid >> 3, d0_ = (tid & 7) * 8;                                   \
    kpr0 = *(const f32x4*)(Kp + (b_ + sr_) * DDIM + d0_);                      \
    kpr1 = *(const f32x4*)(Kp + (b_ + sr_) * DDIM + d0_ + 4);                  \
    vpr0 = *(const f32x4*)(Vp + (b_ + sr_) * VDIM + d0_);                      \
    vpr1 = *(const f32x4*)(Vp + (b_ + sr_) * VDIM + d0_ + 4);                  \
  }

#define WRITE_KV(KB, VB)                                                       \
  {                                                                            \
    int srow = tid >> 3, d0 = (tid & 7) * 8;                                   \
    bf16x8 kb;                                                                 \
    _Pragma("unroll")                                                          \
    for (int j = 0; j < 4; ++j) { kb[j] = (__bf16)kpr0[j]; kb[4 + j] = (__bf16)kpr1[j]; } \
    int koff = (srow * 128 + d0 * 2) ^ KSWZ(srow);                             \
    *(bf16x8*)((KB) + koff) = kb;                                              \
    _Pragma("unroll")                                                          \
    for (int j = 0; j < 8; ++j) {                                              \
      int v = d0 + j;                                                          \
      float x = (j < 4) ? vpr0[j] : vpr1[j - 4];                               \
      int voff = (v * 256 + srow * 2) ^ VSWZ(v);                               \
      *(unsigned short*)((VB) + voff) = bfb(x);                                \
    }                                                                          \
  }

  // lane's mask words for phase P: s = P*128 + sq*32 + 8*st + 4*h + r
#define LOAD_MASK(M8, M32, P)                                                  \
  if constexpr (U8) {                                                          \
    _Pragma("unroll")                                                          \
    for (int st = 0; st < 4; ++st)                                             \
      M8[st] = *(const unsigned*)(mrow8 + (size_t)CLAMPP(P) * PBLK + 8 * st + 4 * h); \
  } else {                                                                     \
    _Pragma("unroll")                                                          \
    for (int st = 0; st < 4; ++st)                                             \
      M32[st] = *(const u32x4*)(mrow32 + (size_t)CLAMPP(P) * PBLK + 8 * st + 4 * h); \
  }

// One phase: QK^T -> mask/softmax -> in-register P exchange -> PV.
#define TILE(KB, VB, MU8, MU32) {                                              \
  f32x16 sacc = zero16();                                                      \
  int srow_ = sq * 32 + lq;                                                    \
  __builtin_amdgcn_s_setprio(1);                                               \
  _Pragma("unroll")                                                            \
  for (int kd = 0; kd < 4; ++kd) {                                             \
    int off = (srow_ * 128 + (32 * kd + 16 * h)) ^ KSWZ(srow_);                \
    bf16x8 kf = *(const bf16x8*)((KB) + off);                                  \
    sacc = __builtin_amdgcn_mfma_f32_32x32x16_bf16(kf, qf[kd], sacc, 0, 0, 0); \
  }                                                                            \
  __builtin_amdgcn_s_setprio(0);                                               \
  float vals[4][4];                                                            \
  float mloc = -INFINITY;                                                      \
  _Pragma("unroll")                                                            \
  for (int st = 0; st < 4; ++st) {                                             \
    bool keep[4];                                                              \
    if constexpr (U8) {                                                        \
      unsigned w_ = MU8[st];                                                   \
      _Pragma("unroll")                                                        \
      for (int r = 0; r < 4; ++r) keep[r] = ((w_ >> (8 * r)) & 0xFFu) != 0u;   \
    } else {                                                                   \
      _Pragma("unroll")                                                        \
      for (int r = 0; r < 4; ++r) keep[r] = MU32[st][r] != 0u;                 \
    }                                                                          \
    _Pragma("unroll")                                                          \
    for (int r = 0; r < 4; ++r) {                                              \
      float v = keep[r] ? sacc[4 * st + r] : -1.0e9f;                          \
      vals[st][r] = v;                                                         \
      mloc = fmaxf(mloc, v);                                                   \
    }                                                                          \
  }                                                                            \
  mloc = fmaxf(mloc, __shfl_xor(mloc, 32));                                    \
  if (!__all(mloc <= m_run + 8.0f)) {      /* defer-max rescale */             \
    float m_new = fmaxf(m_run, mloc);                                          \
    float alpha = __builtin_amdgcn_exp2f(m_run - m_new);                       \
    l_run *= alpha;                                                            \
    _Pragma("unroll")                                                          \
    for (int vt = 0; vt < 2; ++vt)                                             \
      _Pragma("unroll")                                                        \
      for (int r = 0; r < 16; ++r) oacc[vt][r] *= alpha;                       \
    m_run = m_new;                                                             \
  }                                                                            \
  float lsum = 0.f;                                                            \
  unsigned wlo[4], whi[4];                                                     \
  _Pragma("unroll")                                                            \
  for (int st = 0; st < 4; ++st) {                                             \
    float p0 = __builtin_amdgcn_exp2f(vals[st][0] - m_run);                    \
    float p1 = __builtin_amdgcn_exp2f(vals[st][1] - m_run);                    \
    float p2 = __builtin_amdgcn_exp2f(vals[st][2] - m_run);                    \
    float p3 = __builtin_amdgcn_exp2f(vals[st][3] - m_run);                    \
    lsum += (p0 + p1) + (p2 + p3);                                             \
    wlo[st] = pk2(p0, p1);                                                     \
    whi[st] = pk2(p2, p3);                                                     \
  }                                                                            \
  lsum += __shfl_xor(lsum, 32);                                                \
  l_run += lsum;                                                               \
  /* PV B-frag: keep st=2ks2+h, recv partner's st=2ks2+(1-h) (r14-verified) */ \
  _Pragma("unroll")                                                            \
  for (int ks2 = 0; ks2 < 2; ++ks2) {                                          \
    unsigned slo = h ? wlo[2 * ks2] : wlo[2 * ks2 + 1];                        \
    unsigned shi = h ? whi[2 * ks2] : whi[2 * ks2 + 1];                        \
    unsigned rlo = __shfl_xor(slo, 32);                                        \
    unsigned rhi = __shfl_xor(shi, 32);                                        \
    unsigned klo = h ? wlo[2 * ks2 + 1] : wlo[2 * ks2];                        \
    unsigned khi = h ? whi[2 * ks2 + 1] : whi[2 * ks2];                        \
    u32x4 fw;                                                                  \
    fw[0] = h ? rlo : klo;  fw[1] = h ? rhi : khi;                             \
    fw[2] = h ? klo : rlo;  fw[3] = h ? khi : rhi;                             \
    bf16x8 pf = __builtin_bit_cast(bf16x8, fw);                                \
    __builtin_amdgcn_s_setprio(1);                                             \
    _Pragma("unroll")                                                          \
    for (int vt = 0; vt < 2; ++vt) {                                           \
      int vrow = 32 * vt + lq;                                                 \
      int voff = (vrow * 256 + (64 * sq + 32 * ks2 + 16 * h)) ^ VSWZ(vrow);    \
      bf16x8 vf = *(const bf16x8*)((VB) + voff);                               \
      oacc[vt] = __builtin_amdgcn_mfma_f32_32x32x16_bf16(vf, pf, oacc[vt], 0, 0, 0); \
    }                                                                          \
    __builtin_amdgcn_s_setprio(0);                                             \
  }                                                                            \
}

#define PHASE_BODY(P, KBc, VBc, KBn, VBn, MU8, MU32, ML8, ML32) {              \
  PREFETCH_KV((P) + 1);                                                        \
  LOAD_MASK(ML8, ML32, (P) + 1);                                               \
  TILE(KBc, VBc, MU8, MU32);                                                   \
  WRITE_KV(KBn, VBn);                                                          \
  LDS_BARRIER();                                                               \
}

  // prologue
  PREFETCH_KV(0);
  LOAD_MASK(m8A, m32A, 0);
  WRITE_KV(Kb0, Vb0);
  LDS_BARRIER();

  for (int pp = 0; pp < NPHASE; pp += 2) {
    PHASE_BODY(pp,     Kb0, Vb0, Kb1, Vb1, m8A, m32A, m8B, m32B);
    PHASE_BODY(pp + 1, Kb1, Vb1, Kb0, Vb0, m8B, m32B, m8A, m32A);
  }

  // ---- 4-way s-merge (2-round tree) in LDS aliased onto dead K/V arena ----
  // oacc reg -> v = 32vt + 8st + 4h + r (col q = lq). Slot = 32KB: [qtile][64v][32q].
#define PUBLISH(SLOT) {                                                        \
    float* mOs = (float*)LB + (SLOT) * 8192;                                   \
    _Pragma("unroll")                                                          \
    for (int vt = 0; vt < 2; ++vt)                                             \
      _Pragma("unroll")                                                        \
      for (int st = 0; st < 4; ++st)                                           \
        _Pragma("unroll")                                                      \
        for (int r = 0; r < 4; ++r) {                                          \
          int v = 32 * vt + 8 * st + 4 * h + r;                                \
          mOs[((size_t)qtile * 64 + v) * 32 + lq] = oacc[vt][4 * st + r];      \
        }                                                                      \
    if (h == 0) {                                                              \
      mM[SLOT][qtile][0][lq] = m_run;                                          \
      mM[SLOT][qtile][1][lq] = l_run;                                          \
    }                                                                          \
  }
#define MERGE(SLOT) {                                                          \
    float m1 = mM[SLOT][qtile][0][lq];                                         \
    float l1 = mM[SLOT][qtile][1][lq];                                         \
    float mm = fmaxf(m_run, m1);                                               \
    float a0 = __builtin_amdgcn_exp2f(m_run - mm);                             \
    float a1 = __builtin_amdgcn_exp2f(m1 - mm);                                \
    m_run = mm;                                                                \
    l_run = l_run * a0 + l1 * a1;                                              \
    const float* mOs = (const float*)LB + (SLOT) * 8192;                       \
    _Pragma("unroll")                                                          \
    for (int vt = 0; vt < 2; ++vt)                                             \
      _Pragma("unroll")                                                        \
      for (int st = 0; st < 4; ++st)                                           \
        _Pragma("unroll")                                                      \
        for (int r = 0; r < 4; ++r) {                                          \
          int v = 32 * vt + 8 * st + 4 * h + r;                                \
          float o1 = mOs[((size_t)qtile * 64 + v) * 32 + lq];                  \
          oacc[vt][4 * st + r] = oacc[vt][4 * st + r] * a0 + o1 * a1;          \
        }                                                                      \
  }

  if (sq == 1) PUBLISH(0);
  if (sq == 3) PUBLISH(1);
  LDS_BARRIER();
  if (sq == 0) MERGE(0);
  if (sq == 2) MERGE(1);
  LDS_BARRIER();
  if (sq == 2) PUBLISH(0);
  LDS_BARRIER();
  if (sq == 0) {
    MERGE(0);
    float inv_l = 1.0f / l_run;
    float* orow = Op + (size_t)qrow * VDIM;
#pragma unroll
    for (int vt = 0; vt < 2; ++vt) {
#pragma unroll
      for (int st = 0; st < 4; ++st) {
        int v0 = 32 * vt + 8 * st + 4 * h;
        f32x4 o;
#pragma unroll
        for (int r = 0; r < 4; ++r) o[r] = oacc[vt][4 * st + r] * inv_l;
        *(f32x4*)(orow + v0) = o;
      }
    }
  }
#undef PREFETCH_KV
#undef WRITE_KV
#undef LOAD_MASK
#undef TILE
#undef PHASE_BODY
#undef PUBLISH
#undef MERGE
}

extern "C" void kernel_launch(void* const* d_in, const int* in_sizes, int n_in,
                              void* d_out, int out_size, void* d_ws, size_t ws_size,
                              hipStream_t stream) {
  const float* Qg = (const float*)d_in[0];
  const float* Kg = (const float*)d_in[1];
  const float* Vg = (const float*)d_in[2];
  const unsigned char* Mg = (const unsigned char*)d_in[3];
  float* Og = (float*)d_out;

  dim3 grid(NHEADS, QLEN / QBLK);   // 256 blocks; linear id % 8 == head -> head-per-XCD
  dim3 block(1024);
  attn_fwd<true ><<<grid, block, 0, stream>>>(Qg, Kg, Vg, Mg, Og);   // u8 bool mask
  attn_fwd<false><<<grid, block, 0, stream>>>(Qg, Kg, Vg, Mg, Og);   // i32/f32 mask
}